// Round 3
// baseline (8176.734 us; speedup 1.0000x reference)
//
#include <hip/hip_runtime.h>
#include <stdint.h>

#define TT 512
#define BB 32
#define HH 1024

typedef __attribute__((ext_vector_type(8))) short short8;
typedef __attribute__((ext_vector_type(8))) __bf16 bf16x8;
typedef __attribute__((ext_vector_type(16))) float f32x16;

// ---------------- workspace layout (bytes) ----------------
#define OFF_BAR   0u
#define OFF_XBF   1024u                      // [512 t][32 b][512 d] bf16 = 16 MB
#define OFF_WIH0  (OFF_XBF  + 16777216u)     // [2048][512]  bf16 = 2 MB
#define OFF_WHH0  (OFF_WIH0 + 2097152u)      // [2048][1024] bf16 = 4 MB
#define OFF_WIH1  (OFF_WHH0 + 4194304u)      // [2048][1024] bf16 = 4 MB
#define OFF_WHH1  (OFF_WIH1 + 4194304u)      // [2048][1024] bf16 = 4 MB
#define OFF_B0    (OFF_WHH1 + 4194304u)      // [2048] f32  (b_ih0+b_hh0)
#define OFF_B1    (OFF_B0   + 8192u)         // [2048] f32
#define OFF_PRE0  (OFF_B1   + 8192u)         // [2][32][2048] f32 ring = 512 KB
#define OFF_PRE1  (OFF_PRE0 + 524288u)       // [2][32][2048] f32 ring
#define OFF_H0    (OFF_PRE1 + 524288u)       // [2][32][1024] bf16 ring
#define OFF_H1    (OFF_H0   + 131072u)       // [2][32][1024] bf16 ring
#define OFF_H0F   (OFF_H1   + 131072u)       // [2][32][1024] f32 ring (exact state)
#define OFF_H1F   (OFF_H0F  + 262144u)       // [2][32][1024] f32 ring
#define WS_TOTAL  (OFF_H1F  + 262144u)       // ~31.8 MiB

__device__ inline uint16_t f2bf(float f) {
  uint32_t u = __builtin_bit_cast(uint32_t, f);
  u = (u + 0x7fffu + ((u >> 16) & 1u)) >> 16;
  return (uint16_t)u;
}

// async 16B/lane global -> LDS (linear dest = wave-uniform base + lane*16)
__device__ inline void async16(const void* g, void* l) {
  __builtin_amdgcn_global_load_lds(
      (const __attribute__((address_space(1))) unsigned int*)g,
      (__attribute__((address_space(3))) unsigned int*)l, 16, 0, 0);
}

// ---------------- prep: converts, transposes, inits ----------------
__global__ void prep_kernel(
    const float* __restrict__ x,    const float* __restrict__ hx,
    const float* __restrict__ wih0, const float* __restrict__ whh0,
    const float* __restrict__ bih0, const float* __restrict__ bhh0,
    const float* __restrict__ wih1, const float* __restrict__ whh1,
    const float* __restrict__ bih1, const float* __restrict__ bhh1,
    char* __restrict__ ws)
{
  uint16_t* xbf = (uint16_t*)(ws + OFF_XBF);
  uint16_t* w0  = (uint16_t*)(ws + OFF_WIH0);
  uint16_t* wh0 = (uint16_t*)(ws + OFF_WHH0);
  uint16_t* w1  = (uint16_t*)(ws + OFF_WIH1);
  uint16_t* wh1 = (uint16_t*)(ws + OFF_WHH1);
  float* b0 = (float*)(ws + OFF_B0);
  float* b1 = (float*)(ws + OFF_B1);
  uint16_t* h0r = (uint16_t*)(ws + OFF_H0);
  uint16_t* h1r = (uint16_t*)(ws + OFF_H1);
  float* h0f = (float*)(ws + OFF_H0F);
  float* h1f = (float*)(ws + OFF_H1F);

  const long long NX = 8388608, NW0 = 1048576, NWH0 = 2097152, NW1 = 2097152, NWH1 = 2097152;
  const long long NB = 4096, NHX = 65536;
  const long long total = NX + NW0 + NWH0 + NW1 + NWH1 + NB + NHX + 1;

  for (long long i = (long long)blockIdx.x * blockDim.x + threadIdx.x; i < total;
       i += (long long)gridDim.x * blockDim.x) {
    long long j = i;
    if (j < NX) {                       // x[b][t][d] fp32 -> xbf[t][b][d] bf16
      int t = (int)(j >> 14), r = (int)(j & 16383), b = r >> 9, d = r & 511;
      xbf[j] = f2bf(x[(long long)b * 262144 + (long long)t * 512 + d]);
    } else if ((j -= NX) < NW0) {
      w0[j] = f2bf(wih0[j]);
    } else if ((j -= NW0) < NWH0) {
      wh0[j] = f2bf(whh0[j]);
    } else if ((j -= NWH0) < NW1) {
      w1[j] = f2bf(wih1[j]);
    } else if ((j -= NW1) < NWH1) {
      wh1[j] = f2bf(whh1[j]);
    } else if ((j -= NWH1) < NB) {
      if (j < 2048) b0[j] = bih0[j] + bhh0[j];
      else          b1[j - 2048] = bih1[j - 2048] + bhh1[j - 2048];
    } else if ((j -= NB) < NHX) {       // hx -> ring slot 1 (t = -1 parity)
      float v = hx[j];
      if (j < 32768) { h0r[32768 + j] = f2bf(v); h0f[32768 + j] = v; }
      else { h1r[32768 + (j - 32768)] = f2bf(v); h1f[32768 + (j - 32768)] = v; }
    } else {
      *(uint32_t*)(ws + OFF_BAR) = 0u;
    }
  }
}

// ---------------- persistent pipelined recurrence ----------------
// 256 WGs of 256 threads (plain launch; 1 WG/CU trivially co-resident).
// role = blockIdx/64 (also the pipeline lag):
//  0: pre0[s]   = x[s]   @ Wih0^T           (K=512)
//  1: h0[s-1]   = gate(pre0 + h0 @ Whh0^T)  (K=1024)
//  2: pre1[s-2] = h0[s-2]@ Wih1^T           (K=1024)
//  3: h1[s-3]   = gate(pre1 + h1 @ Whh1^T)  (K=1024), writes d_out
// Each WG owns 16 h-cols => 32 gate cols ([16 U] + [16 O]).
__global__ void __launch_bounds__(256) gru_persist(char* __restrict__ ws, float* __restrict__ out)
{
  __shared__ __align__(16) char smem[65536];

  uint32_t* bar = (uint32_t*)(ws + OFF_BAR);
  const uint16_t* xbf = (const uint16_t*)(ws + OFF_XBF);
  float* pre0 = (float*)(ws + OFF_PRE0);
  float* pre1 = (float*)(ws + OFF_PRE1);
  uint16_t* h0r  = (uint16_t*)(ws + OFF_H0);
  uint16_t* h1r  = (uint16_t*)(ws + OFF_H1);
  float*    h0f  = (float*)(ws + OFF_H0F);
  float*    h1f  = (float*)(ws + OFF_H1F);

  const int tid  = threadIdx.x;
  const int wave = tid >> 6;
  const int lane = tid & 63;
  const int role = blockIdx.x >> 6;
  const int g    = blockIdx.x & 63;

  const int K     = (role == 0) ? 512 : 1024;
  const int KB2   = K * 2;                 // bytes per row
  const int shift = (role == 0) ? 10 : 11; // log2(KB2)
  const int nfrag = K >> 6;                // MFMAs per wave: 8 or 16
  const int kbase = wave * (K >> 2);       // K-split across 4 waves

  const uint16_t* W =
      (role == 0) ? (const uint16_t*)(ws + OFF_WIH0) :
      (role == 1) ? (const uint16_t*)(ws + OFF_WHH0) :
      (role == 2) ? (const uint16_t*)(ws + OFF_WIH1) :
                    (const uint16_t*)(ws + OFF_WHH1);
  const float* bias   = (role == 1) ? (const float*)(ws + OFF_B0) : (const float*)(ws + OFF_B1);
  const float* pre_rd = (role == 1) ? pre0 : pre1;
  float*       pre_wr = (role == 0) ? pre0 : pre1;
  const uint16_t* Aring  = (role == 3) ? h1r : h0r;
  uint16_t* h_wr  = (role == 1) ? h0r : h1r;
  float*    hfp   = (role == 1) ? h0f : h1f;

  // ---- stage weight slice [32 gate-rows][K] linearly into LDS (one-time) ----
  {
    const int rsh = (role == 0) ? 6 : 7;   // 16B chunks per row: 64 or 128
    const int cpr = 1 << rsh;
    const int iters = (32 * cpr) >> 8;
    for (int i = 0; i < iters; ++i) {
      int c   = (i * 4 + wave) * 64 + lane;
      int row = c >> rsh;
      int ir  = c & (cpr - 1);
      int wr  = (row < 16) ? (16 * g + row) : (1024 + 16 * g + (row - 16));
      async16(W + (size_t)wr * K + (size_t)ir * 8, smem + (size_t)(i * 4 + wave) * 1024);
    }
    asm volatile("s_waitcnt vmcnt(0)" ::: "memory");
    __syncthreads();
  }

  // ---- B fragments -> registers (persistent). lane: col=lane&31, k=(lane>>5)*8.. ----
  bf16x8 breg[16];
  {
    const int bcol  = lane & 31;
    const int khalf = (lane >> 5) * 8;
#pragma unroll
    for (int it = 0; it < 16; ++it) {
      if (it < nfrag) {
        int kk = kbase + it * 16 + khalf;
        breg[it] = __builtin_bit_cast(bf16x8,
                     *(const short8*)(smem + ((size_t)bcol * K + kk) * 2));
      }
    }
  }
  __syncthreads();

  // per-lane output-tile constants (C layout: col=lane&31, row=(r&3)+8*(r>>2)+4*(lane>>5))
  const int col  = lane & 31;
  const bool isU = (col < 16);
  const int gcol = isU ? (16 * g + col) : (1024 + 16 * g + (col - 16));
  const int rowb = (lane >> 5) * 4;
  const float bias_l = (role == 1 || role == 3) ? bias[gcol] : 0.0f;
  const int hcol = 16 * g + (col & 15);

  for (int s = 0; s < 515; ++s) {
    const unsigned tu = (unsigned)(s - role);
    if (tu < 512u) {
      const int t = s - role;

      // ---- early scalar prefetch (roles 1,3): gate-init + exact fp32 h_prev ----
      float pinit[16], hprev[16];
      if (role == 1 || role == 3) {
        const float* pr = pre_rd + (size_t)(t & 1) * (BB * 2048) + gcol;
        const float* hp = hfp    + (size_t)(s & 1) * (BB * 1024) + hcol;
#pragma unroll
        for (int r = 0; r < 16; ++r) {
          int b = (r & 3) + 8 * (r >> 2) + rowb;
          pinit[r] = pr[(size_t)b * 2048];
          hprev[r] = hp[(size_t)b * 1024];
        }
      }

      // ---- stage A [32][K] bf16 -> LDS, source pre-swizzled (read-side XOR matches) ----
      {
        const char* Ag = (role == 0)
            ? (const char*)(xbf + (size_t)t * (BB * 512))
            : (const char*)(Aring + (size_t)(s & 1) * (BB * 1024));
        const int iters = K >> 6;          // 8 (32KB) or 16 (64KB)
        for (int i = 0; i < iters; ++i) {
          int L = (((i * 4 + wave) * 64) + lane) * 16;
          int src = L ^ (((L >> shift) & 15) << 4);
          async16(Ag + src, smem + (size_t)(i * 4 + wave) * 1024);
        }
        asm volatile("s_waitcnt vmcnt(0)" ::: "memory");
        __syncthreads();
      }

      // ---- MFMA (builtin: compiler owns hazards/scheduling) ----
      f32x16 acc0, acc1;
#pragma unroll
      for (int r = 0; r < 16; ++r) { acc0[r] = 0.0f; acc1[r] = 0.0f; }
      {
        const int arow   = lane & 31;
        const int abyte0 = arow * KB2;
        const int swz    = (arow & 15) << 4;
        const int ka     = (kbase + (lane >> 5) * 8) * 2;
#pragma unroll
        for (int it = 0; it < 16; ++it) {
          if (it < nfrag) {
            int addr = (abyte0 + ka + it * 32) ^ swz;
            bf16x8 a = __builtin_bit_cast(bf16x8, *(const short8*)(smem + addr));
            if (it & 1)
              acc1 = __builtin_amdgcn_mfma_f32_32x32x16_bf16(a, breg[it], acc1, 0, 0, 0);
            else
              acc0 = __builtin_amdgcn_mfma_f32_32x32x16_bf16(a, breg[it], acc0, 0, 0, 0);
          }
        }
      }
      f32x16 accT;
#pragma unroll
      for (int r = 0; r < 16; ++r) accT[r] = acc0[r] + acc1[r];

      // ---- cross-wave K reduction via LDS tree (reuses A buffer) ----
      float* red = (float*)smem;
      __syncthreads();                     // all A reads done before overwrite
      if (wave >= 2) {
#pragma unroll
        for (int r = 0; r < 16; ++r) red[(wave - 2) * 1024 + r * 64 + lane] = accT[r];
      }
      __syncthreads();
      if (wave < 2) {
#pragma unroll
        for (int r = 0; r < 16; ++r) accT[r] += red[wave * 1024 + r * 64 + lane];
      }
      __syncthreads();
      if (wave == 1) {
#pragma unroll
        for (int r = 0; r < 16; ++r) red[r * 64 + lane] = accT[r];
      }
      __syncthreads();
      if (wave == 0) {
#pragma unroll
        for (int r = 0; r < 16; ++r) accT[r] += red[r * 64 + lane];

        if (role == 0 || role == 2) {
          // pre producers: store raw projection fp32 to ring
          float* dst = pre_wr + (size_t)(t & 1) * (BB * 2048) + gcol;
#pragma unroll
          for (int r = 0; r < 16; ++r) {
            int b = (r & 3) + 8 * (r >> 2) + rowb;
            dst[(size_t)b * 2048] = accT[r];
          }
        } else {
          // recurrent roles: gates -> activation -> h update
          uint16_t* hb = h_wr + (size_t)(t & 1) * (BB * 1024) + hcol;
          float*    hf = hfp  + (size_t)(t & 1) * (BB * 1024) + hcol;
#pragma unroll
          for (int r = 0; r < 16; ++r) {
            float c = accT[r] + pinit[r] + bias_l;
            float v = isU ? (1.0f / (1.0f + __expf(-c))) : fmaxf(c, 0.0f);
            float p = __shfl_xor(v, 16);   // pair U-lane with its O-lane
            if (isU) {
              int b = (r & 3) + 8 * (r >> 2) + rowb;
              float hn = v * hprev[r] + (1.0f - v) * p;
              hb[(size_t)b * 1024] = f2bf(hn);
              hf[(size_t)b * 1024] = hn;
              if (role == 3)
                out[(size_t)b * (TT * HH) + (size_t)t * HH + hcol] = hn;
            }
          }
        }
      }
    } // active

    // ---- device-scope step barrier ----
    __syncthreads();
    if (tid == 0) {
      __builtin_amdgcn_fence(__ATOMIC_RELEASE, "agent");
      __hip_atomic_fetch_add(bar, 1u, __ATOMIC_RELAXED, __HIP_MEMORY_SCOPE_AGENT);
      const uint32_t tgt = (uint32_t)(s + 1) * 256u;
      while (__hip_atomic_load(bar, __ATOMIC_RELAXED, __HIP_MEMORY_SCOPE_AGENT) < tgt)
        __builtin_amdgcn_s_sleep(2);
      __builtin_amdgcn_fence(__ATOMIC_ACQUIRE, "agent");
    }
    __syncthreads();
  }
}

extern "C" void kernel_launch(void* const* d_in, const int* in_sizes, int n_in,
                              void* d_out, int out_size, void* d_ws, size_t ws_size,
                              hipStream_t stream) {
  const float* x    = (const float*)d_in[0];
  const float* hx   = (const float*)d_in[1];
  const float* wih0 = (const float*)d_in[2];
  const float* whh0 = (const float*)d_in[3];
  const float* bih0 = (const float*)d_in[4];
  const float* bhh0 = (const float*)d_in[5];
  const float* wih1 = (const float*)d_in[6];
  const float* whh1 = (const float*)d_in[7];
  const float* bih1 = (const float*)d_in[8];
  const float* bhh1 = (const float*)d_in[9];
  char* ws   = (char*)d_ws;
  float* out = (float*)d_out;

  hipLaunchKernelGGL(prep_kernel, dim3(2048), dim3(256), 0, stream,
                     x, hx, wih0, whh0, bih0, bhh0, wih1, whh1, bih1, bhh1, ws);

  // Plain launch: 256 WGs x 64KB LDS x 4 waves => guaranteed co-resident
  // (<=1 WG/CU on 256 CUs); hand-rolled device barrier handles sync.
  hipLaunchKernelGGL(gru_persist, dim3(256), dim3(256), 0, stream, ws, out);
}

// Round 4
// 6029.446 us; speedup vs baseline: 1.3561x; 1.3561x over previous
//
#include <hip/hip_runtime.h>
#include <stdint.h>

#define TT 512
#define BB 32
#define HH 1024

typedef __attribute__((ext_vector_type(8))) short short8;
typedef __attribute__((ext_vector_type(8))) __bf16 bf16x8;
typedef __attribute__((ext_vector_type(16))) float f32x16;

// ---------------- workspace layout (bytes) ----------------
// Barrier region (4 KB): [0..1023] grpCnt[8] @128B stride; [1024] rootCnt;
//                        [2048..3071] grpFlag[8] @128B stride.
#define OFF_BAR   0u
#define OFF_XBF   4096u                      // [512 t][32 b][512 d] bf16 = 16 MB
#define OFF_WIH0  (OFF_XBF  + 16777216u)     // [2048][512]  bf16 = 2 MB
#define OFF_WHH0  (OFF_WIH0 + 2097152u)      // [2048][1024] bf16 = 4 MB
#define OFF_WIH1  (OFF_WHH0 + 4194304u)      // [2048][1024] bf16 = 4 MB
#define OFF_WHH1  (OFF_WIH1 + 4194304u)      // [2048][1024] bf16 = 4 MB
#define OFF_B0    (OFF_WHH1 + 4194304u)      // [2048] f32  (b_ih0+b_hh0)
#define OFF_B1    (OFF_B0   + 8192u)         // [2048] f32
#define OFF_PRE0  (OFF_B1   + 8192u)         // [2][32][2048] f32 ring = 512 KB
#define OFF_PRE1  (OFF_PRE0 + 524288u)       // [2][32][2048] f32 ring
#define OFF_H0    (OFF_PRE1 + 524288u)       // [2][32][1024] bf16 ring
#define OFF_H1    (OFF_H0   + 131072u)       // [2][32][1024] bf16 ring
#define OFF_H0F   (OFF_H1   + 131072u)       // [2][32][1024] f32 ring (exact state)
#define OFF_H1F   (OFF_H0F  + 262144u)       // [2][32][1024] f32 ring
#define WS_TOTAL  (OFF_H1F  + 262144u)       // ~31.8 MiB

__device__ inline uint16_t f2bf(float f) {
  uint32_t u = __builtin_bit_cast(uint32_t, f);
  u = (u + 0x7fffu + ((u >> 16) & 1u)) >> 16;
  return (uint16_t)u;
}

// async 16B/lane global -> LDS (linear dest = wave-uniform base + lane*16)
__device__ inline void async16(const void* g, void* l) {
  __builtin_amdgcn_global_load_lds(
      (const __attribute__((address_space(1))) unsigned int*)g,
      (__attribute__((address_space(3))) unsigned int*)l, 16, 0, 0);
}

// ---------------- prep: converts, transposes, inits ----------------
__global__ void prep_kernel(
    const float* __restrict__ x,    const float* __restrict__ hx,
    const float* __restrict__ wih0, const float* __restrict__ whh0,
    const float* __restrict__ bih0, const float* __restrict__ bhh0,
    const float* __restrict__ wih1, const float* __restrict__ whh1,
    const float* __restrict__ bih1, const float* __restrict__ bhh1,
    char* __restrict__ ws)
{
  uint16_t* xbf = (uint16_t*)(ws + OFF_XBF);
  uint16_t* w0  = (uint16_t*)(ws + OFF_WIH0);
  uint16_t* wh0 = (uint16_t*)(ws + OFF_WHH0);
  uint16_t* w1  = (uint16_t*)(ws + OFF_WIH1);
  uint16_t* wh1 = (uint16_t*)(ws + OFF_WHH1);
  float* b0 = (float*)(ws + OFF_B0);
  float* b1 = (float*)(ws + OFF_B1);
  uint16_t* h0r = (uint16_t*)(ws + OFF_H0);
  uint16_t* h1r = (uint16_t*)(ws + OFF_H1);
  float* h0f = (float*)(ws + OFF_H0F);
  float* h1f = (float*)(ws + OFF_H1F);

  const long long NX = 8388608, NW0 = 1048576, NWH0 = 2097152, NW1 = 2097152, NWH1 = 2097152;
  const long long NB = 4096, NHX = 65536, NBAR = 1024;
  const long long total = NX + NW0 + NWH0 + NW1 + NWH1 + NB + NHX + NBAR;

  for (long long i = (long long)blockIdx.x * blockDim.x + threadIdx.x; i < total;
       i += (long long)gridDim.x * blockDim.x) {
    long long j = i;
    if (j < NX) {                       // x[b][t][d] fp32 -> xbf[t][b][d] bf16
      int t = (int)(j >> 14), r = (int)(j & 16383), b = r >> 9, d = r & 511;
      xbf[j] = f2bf(x[(long long)b * 262144 + (long long)t * 512 + d]);
    } else if ((j -= NX) < NW0) {
      w0[j] = f2bf(wih0[j]);
    } else if ((j -= NW0) < NWH0) {
      wh0[j] = f2bf(whh0[j]);
    } else if ((j -= NWH0) < NW1) {
      w1[j] = f2bf(wih1[j]);
    } else if ((j -= NW1) < NWH1) {
      wh1[j] = f2bf(whh1[j]);
    } else if ((j -= NWH1) < NB) {
      if (j < 2048) b0[j] = bih0[j] + bhh0[j];
      else          b1[j - 2048] = bih1[j - 2048] + bhh1[j - 2048];
    } else if ((j -= NB) < NHX) {       // hx -> ring slot 1 (t = -1 parity)
      float v = hx[j];
      if (j < 32768) { h0r[32768 + j] = f2bf(v); h0f[32768 + j] = v; }
      else { h1r[32768 + (j - 32768)] = f2bf(v); h1f[32768 + (j - 32768)] = v; }
    } else {                            // zero the whole barrier region (4 KB)
      j -= NHX;
      ((uint32_t*)(ws + OFF_BAR))[j] = 0u;
    }
  }
}

// ---------------- persistent pipelined recurrence ----------------
// 256 WGs of 256 threads (plain launch; 1 WG/CU trivially co-resident).
// role = blockIdx/64 (also the pipeline lag):
//  0: pre0[s]   = x[s]   @ Wih0^T           (K=512)
//  1: h0[s-1]   = gate(pre0 + h0 @ Whh0^T)  (K=1024)
//  2: pre1[s-2] = h0[s-2]@ Wih1^T           (K=1024)
//  3: h1[s-3]   = gate(pre1 + h1 @ Whh1^T)  (K=1024), writes d_out
// Each WG owns 16 h-cols => 32 gate cols ([16 U] + [16 O]).
__global__ void __launch_bounds__(256) gru_persist(char* __restrict__ ws, float* __restrict__ out)
{
  __shared__ __align__(16) char smem[65536];

  const uint16_t* xbf = (const uint16_t*)(ws + OFF_XBF);
  float* pre0 = (float*)(ws + OFF_PRE0);
  float* pre1 = (float*)(ws + OFF_PRE1);
  uint16_t* h0r  = (uint16_t*)(ws + OFF_H0);
  uint16_t* h1r  = (uint16_t*)(ws + OFF_H1);
  float*    h0f  = (float*)(ws + OFF_H0F);
  float*    h1f  = (float*)(ws + OFF_H1F);

  const int tid  = threadIdx.x;
  const int wave = tid >> 6;
  const int lane = tid & 63;
  const int bid  = blockIdx.x;
  const int role = bid >> 6;
  const int g    = bid & 63;

  // two-level barrier lines (group by bid&7: XCD-local if round-robin holds;
  // correct regardless of placement)
  uint32_t* grpCnt  = (uint32_t*)(ws + OFF_BAR + (size_t)(bid & 7) * 128);
  uint32_t* rootCnt = (uint32_t*)(ws + OFF_BAR + 1024);
  uint32_t* grpFlag = (uint32_t*)(ws + OFF_BAR + 2048 + (size_t)(bid & 7) * 128);

  const int K     = (role == 0) ? 512 : 1024;
  const int KB2   = K * 2;                 // bytes per row
  const int shift = (role == 0) ? 10 : 11; // log2(KB2)
  const int nfrag = K >> 6;                // MFMAs per wave: 8 or 16
  const int kbase = wave * (K >> 2);       // K-split across 4 waves

  const uint16_t* W =
      (role == 0) ? (const uint16_t*)(ws + OFF_WIH0) :
      (role == 1) ? (const uint16_t*)(ws + OFF_WHH0) :
      (role == 2) ? (const uint16_t*)(ws + OFF_WIH1) :
                    (const uint16_t*)(ws + OFF_WHH1);
  const float* bias   = (role == 1) ? (const float*)(ws + OFF_B0) : (const float*)(ws + OFF_B1);
  const float* pre_rd = (role == 1) ? pre0 : pre1;
  float*       pre_wr = (role == 0) ? pre0 : pre1;
  const uint16_t* Aring  = (role == 3) ? h1r : h0r;
  uint16_t* h_wr  = (role == 1) ? h0r : h1r;
  float*    hfp   = (role == 1) ? h0f : h1f;

  // ---- stage weight slice [32 gate-rows][K] linearly into LDS (one-time) ----
  {
    const int rsh = (role == 0) ? 6 : 7;   // 16B chunks per row: 64 or 128
    const int cpr = 1 << rsh;
    const int iters = (32 * cpr) >> 8;
    for (int i = 0; i < iters; ++i) {
      int c   = (i * 4 + wave) * 64 + lane;
      int row = c >> rsh;
      int ir  = c & (cpr - 1);
      int wr  = (row < 16) ? (16 * g + row) : (1024 + 16 * g + (row - 16));
      async16(W + (size_t)wr * K + (size_t)ir * 8, smem + (size_t)(i * 4 + wave) * 1024);
    }
    asm volatile("s_waitcnt vmcnt(0)" ::: "memory");
    __syncthreads();
  }

  // ---- B fragments -> registers (persistent). lane: col=lane&31, k=(lane>>5)*8.. ----
  bf16x8 breg[16];
  {
    const int bcol  = lane & 31;
    const int khalf = (lane >> 5) * 8;
#pragma unroll
    for (int it = 0; it < 16; ++it) {
      if (it < nfrag) {
        int kk = kbase + it * 16 + khalf;
        breg[it] = __builtin_bit_cast(bf16x8,
                     *(const short8*)(smem + ((size_t)bcol * K + kk) * 2));
      }
    }
  }
  __syncthreads();

  // per-lane output-tile constants (C layout: col=lane&31, row=(r&3)+8*(r>>2)+4*(lane>>5))
  const int col  = lane & 31;
  const bool isU = (col < 16);
  const int gcol = isU ? (16 * g + col) : (1024 + 16 * g + (col - 16));
  const int rowb = (lane >> 5) * 4;
  const float bias_l = (role == 1 || role == 3) ? bias[gcol] : 0.0f;
  const int hcol = 16 * g + (col & 15);

  for (int s = 0; s < 515; ++s) {
    const unsigned tu = (unsigned)(s - role);
    if (tu < 512u) {
      const int t = s - role;

      // ---- early scalar prefetch (roles 1,3): gate-init + exact fp32 h_prev ----
      float pinit[16], hprev[16];
      if (role == 1 || role == 3) {
        const float* pr = pre_rd + (size_t)(t & 1) * (BB * 2048) + gcol;
        const float* hp = hfp    + (size_t)(s & 1) * (BB * 1024) + hcol;
#pragma unroll
        for (int r = 0; r < 16; ++r) {
          int b = (r & 3) + 8 * (r >> 2) + rowb;
          pinit[r] = pr[(size_t)b * 2048];
          hprev[r] = hp[(size_t)b * 1024];
        }
      }

      // ---- stage A [32][K] bf16 -> LDS, source pre-swizzled (read-side XOR matches) ----
      {
        const char* Ag = (role == 0)
            ? (const char*)(xbf + (size_t)t * (BB * 512))
            : (const char*)(Aring + (size_t)(s & 1) * (BB * 1024));
        const int iters = K >> 6;          // 8 (32KB) or 16 (64KB)
        for (int i = 0; i < iters; ++i) {
          int L = (((i * 4 + wave) * 64) + lane) * 16;
          int src = L ^ (((L >> shift) & 15) << 4);
          async16(Ag + src, smem + (size_t)(i * 4 + wave) * 1024);
        }
        asm volatile("s_waitcnt vmcnt(0)" ::: "memory");
        __syncthreads();
      }

      // ---- MFMA (builtin: compiler owns hazards/scheduling) ----
      f32x16 acc0, acc1;
#pragma unroll
      for (int r = 0; r < 16; ++r) { acc0[r] = 0.0f; acc1[r] = 0.0f; }
      {
        const int arow   = lane & 31;
        const int abyte0 = arow * KB2;
        const int swz    = (arow & 15) << 4;
        const int ka     = (kbase + (lane >> 5) * 8) * 2;
#pragma unroll
        for (int it = 0; it < 16; ++it) {
          if (it < nfrag) {
            int addr = (abyte0 + ka + it * 32) ^ swz;
            bf16x8 a = __builtin_bit_cast(bf16x8, *(const short8*)(smem + addr));
            if (it & 1)
              acc1 = __builtin_amdgcn_mfma_f32_32x32x16_bf16(a, breg[it], acc1, 0, 0, 0);
            else
              acc0 = __builtin_amdgcn_mfma_f32_32x32x16_bf16(a, breg[it], acc0, 0, 0, 0);
          }
        }
      }
      f32x16 accT;
#pragma unroll
      for (int r = 0; r < 16; ++r) accT[r] = acc0[r] + acc1[r];

      // ---- cross-wave K reduction via LDS tree (reuses A buffer) ----
      float* red = (float*)smem;
      __syncthreads();                     // all A reads done before overwrite
      if (wave >= 2) {
#pragma unroll
        for (int r = 0; r < 16; ++r) red[(wave - 2) * 1024 + r * 64 + lane] = accT[r];
      }
      __syncthreads();
      if (wave < 2) {
#pragma unroll
        for (int r = 0; r < 16; ++r) accT[r] += red[wave * 1024 + r * 64 + lane];
      }
      __syncthreads();
      if (wave == 1) {
#pragma unroll
        for (int r = 0; r < 16; ++r) red[r * 64 + lane] = accT[r];
      }
      __syncthreads();
      if (wave == 0) {
#pragma unroll
        for (int r = 0; r < 16; ++r) accT[r] += red[r * 64 + lane];

        if (role == 0 || role == 2) {
          // pre producers: store raw projection fp32 to ring
          float* dst = pre_wr + (size_t)(t & 1) * (BB * 2048) + gcol;
#pragma unroll
          for (int r = 0; r < 16; ++r) {
            int b = (r & 3) + 8 * (r >> 2) + rowb;
            dst[(size_t)b * 2048] = accT[r];
          }
        } else {
          // recurrent roles: gates -> activation -> h update
          uint16_t* hb = h_wr + (size_t)(t & 1) * (BB * 1024) + hcol;
          float*    hf = hfp  + (size_t)(t & 1) * (BB * 1024) + hcol;
#pragma unroll
          for (int r = 0; r < 16; ++r) {
            float c = accT[r] + pinit[r] + bias_l;
            float v = isU ? (1.0f / (1.0f + __expf(-c))) : fmaxf(c, 0.0f);
            float p = __shfl_xor(v, 16);   // pair U-lane with its O-lane
            if (isU) {
              int b = (r & 3) + 8 * (r >> 2) + rowb;
              float hn = v * hprev[r] + (1.0f - v) * p;
              hb[(size_t)b * 1024] = f2bf(hn);
              hf[(size_t)b * 1024] = hn;
              if (role == 3)
                out[(size_t)b * (TT * HH) + (size_t)t * HH + hcol] = hn;
            }
          }
        }
      }
    } // active

    // ---- device-scope step barrier: two-level tree (8 groups x 32) ----
    __syncthreads();
    if (tid == 0) {
      __builtin_amdgcn_fence(__ATOMIC_RELEASE, "agent");
      uint32_t old = __hip_atomic_fetch_add(grpCnt, 1u, __ATOMIC_RELAXED,
                                            __HIP_MEMORY_SCOPE_AGENT);
      if (old == (uint32_t)s * 32u + 31u) {
        // last of group: arrive at root, wait all 8 groups, release own group
        __hip_atomic_fetch_add(rootCnt, 1u, __ATOMIC_RELAXED,
                               __HIP_MEMORY_SCOPE_AGENT);
        while (__hip_atomic_load(rootCnt, __ATOMIC_RELAXED,
                                 __HIP_MEMORY_SCOPE_AGENT) < (uint32_t)(s + 1) * 8u)
          __builtin_amdgcn_s_sleep(1);
        __hip_atomic_store(grpFlag, (uint32_t)(s + 1), __ATOMIC_RELAXED,
                           __HIP_MEMORY_SCOPE_AGENT);
      } else {
        while (__hip_atomic_load(grpFlag, __ATOMIC_RELAXED,
                                 __HIP_MEMORY_SCOPE_AGENT) < (uint32_t)(s + 1))
          __builtin_amdgcn_s_sleep(1);
      }
      __builtin_amdgcn_fence(__ATOMIC_ACQUIRE, "agent");
    }
    __syncthreads();
  }
}

extern "C" void kernel_launch(void* const* d_in, const int* in_sizes, int n_in,
                              void* d_out, int out_size, void* d_ws, size_t ws_size,
                              hipStream_t stream) {
  const float* x    = (const float*)d_in[0];
  const float* hx   = (const float*)d_in[1];
  const float* wih0 = (const float*)d_in[2];
  const float* whh0 = (const float*)d_in[3];
  const float* bih0 = (const float*)d_in[4];
  const float* bhh0 = (const float*)d_in[5];
  const float* wih1 = (const float*)d_in[6];
  const float* whh1 = (const float*)d_in[7];
  const float* bih1 = (const float*)d_in[8];
  const float* bhh1 = (const float*)d_in[9];
  char* ws   = (char*)d_ws;
  float* out = (float*)d_out;

  hipLaunchKernelGGL(prep_kernel, dim3(2048), dim3(256), 0, stream,
                     x, hx, wih0, whh0, bih0, bhh0, wih1, whh1, bih1, bhh1, ws);

  // Plain launch: 256 WGs x 64KB LDS x 4 waves => guaranteed co-resident
  // (<=1 WG/CU on 256 CUs); hand-rolled device barrier handles sync.
  hipLaunchKernelGGL(gru_persist, dim3(256), dim3(256), 0, stream, ws, out);
}

// Round 6
// 4944.532 us; speedup vs baseline: 1.6537x; 1.2194x over previous
//
#include <hip/hip_runtime.h>
#include <stdint.h>

#define TT 512
#define BB 32
#define HH 1024

typedef __attribute__((ext_vector_type(8))) short short8;
typedef __attribute__((ext_vector_type(8))) __bf16 bf16x8;
typedef __attribute__((ext_vector_type(16))) float f32x16;

// ---------------- workspace layout (bytes) ----------------
// Barrier region 8KB: grpCnt A lines @0..1023 (8x128B), grpCnt B @1024..2047,
// rootA @2048, rootB @2176, grpFlag A @4096..5119, grpFlag B @5120..6143.
#define OFF_BAR   0u
#define OFF_XBF   8192u                      // [512 t][32 b][512 d] bf16 = 16 MB
#define OFF_WIH0  (OFF_XBF  + 16777216u)     // [2048][512]  bf16
#define OFF_WHH0  (OFF_WIH0 + 2097152u)      // [2048][1024] bf16
#define OFF_WIH1  (OFF_WHH0 + 4194304u)      // [2048][1024] bf16
#define OFF_WHH1  (OFF_WIH1 + 4194304u)      // [2048][1024] bf16
#define OFF_B0    (OFF_WHH1 + 4194304u)      // [2048] f32 (b_ih0+b_hh0)
#define OFF_B1    (OFF_B0   + 8192u)         // [2048] f32
#define OFF_H0    (OFF_B1   + 8192u)         // [8][32][1024] bf16 ring (depth 8)
#define OFF_H0F   (OFF_H0   + 524288u)       // [2][32][1024] f32 (exact h0 state)
#define OFF_H1    (OFF_H0F  + 262144u)       // [2][32][1024] bf16 ring
#define OFF_H1F   (OFF_H1   + 131072u)       // [2][32][1024] f32 (exact h1 state)
#define WS_TOTAL  (OFF_H1F  + 262144u)       // ~31.1 MiB

__device__ inline uint16_t f2bf(float f) {
  uint32_t u = __builtin_bit_cast(uint32_t, f);
  u = (u + 0x7fffu + ((u >> 16) & 1u)) >> 16;
  return (uint16_t)u;
}

// async 16B/lane global -> LDS. Source per-lane; LDS dest wave-uniform base
// (HW scatters lane i to base + i*16).
__device__ inline void async16(const void* g, void* l) {
  __builtin_amdgcn_global_load_lds(
      (const __attribute__((address_space(1))) unsigned int*)g,
      (__attribute__((address_space(3))) unsigned int*)l, 16, 0, 0);
}

// ---------------- prep: converts, transposes, inits ----------------
__global__ void prep_kernel(
    const float* __restrict__ x,    const float* __restrict__ hx,
    const float* __restrict__ wih0, const float* __restrict__ whh0,
    const float* __restrict__ bih0, const float* __restrict__ bhh0,
    const float* __restrict__ wih1, const float* __restrict__ whh1,
    const float* __restrict__ bih1, const float* __restrict__ bhh1,
    char* __restrict__ ws)
{
  uint16_t* xbf = (uint16_t*)(ws + OFF_XBF);
  uint16_t* w0  = (uint16_t*)(ws + OFF_WIH0);
  uint16_t* wh0 = (uint16_t*)(ws + OFF_WHH0);
  uint16_t* w1  = (uint16_t*)(ws + OFF_WIH1);
  uint16_t* wh1 = (uint16_t*)(ws + OFF_WHH1);
  float* b0 = (float*)(ws + OFF_B0);
  float* b1 = (float*)(ws + OFF_B1);
  uint16_t* h0r = (uint16_t*)(ws + OFF_H0);
  uint16_t* h1r = (uint16_t*)(ws + OFF_H1);
  float* h0f = (float*)(ws + OFF_H0F);
  float* h1f = (float*)(ws + OFF_H1F);

  const long long NX = 8388608, NW0 = 1048576, NWH0 = 2097152, NW1 = 2097152, NWH1 = 2097152;
  const long long NB = 4096, NHX = 65536, NBAR = 2048;
  const long long total = NX + NW0 + NWH0 + NW1 + NWH1 + NB + NHX + NBAR;

  for (long long i = (long long)blockIdx.x * blockDim.x + threadIdx.x; i < total;
       i += (long long)gridDim.x * blockDim.x) {
    long long j = i;
    if (j < NX) {                       // x[b][t][d] fp32 -> xbf[t][b][d] bf16
      int t = (int)(j >> 14), r = (int)(j & 16383), b = r >> 9, d = r & 511;
      xbf[j] = f2bf(x[(long long)b * 262144 + (long long)t * 512 + d]);
    } else if ((j -= NX) < NW0) {
      w0[j] = f2bf(wih0[j]);
    } else if ((j -= NW0) < NWH0) {
      wh0[j] = f2bf(whh0[j]);
    } else if ((j -= NWH0) < NW1) {
      w1[j] = f2bf(wih1[j]);
    } else if ((j -= NW1) < NWH1) {
      wh1[j] = f2bf(whh1[j]);
    } else if ((j -= NWH1) < NB) {
      if (j < 2048) b0[j] = bih0[j] + bhh0[j];
      else          b1[j - 2048] = bih1[j - 2048] + bhh1[j - 2048];
    } else if ((j -= NB) < NHX) {       // hx -> t=-1 ring slots
      float v = hx[j];
      if (j < 32768) {                  // h0[-1]: bf16 slot 7 (t&7), f32 slot 1 (t&1)
        h0r[7 * 32768 + j] = f2bf(v);
        h0f[32768 + j] = v;
      } else {                          // h1[-1]: slot 1 both
        int jj = (int)(j - 32768);
        h1r[32768 + jj] = f2bf(v);
        h1f[32768 + jj] = v;
      }
    } else {                            // zero barrier region (8 KB)
      j -= NHX;
      ((uint32_t*)(ws + OFF_BAR))[j] = 0u;
    }
  }
}

// ---------------- persistent 2-role recurrence, decoupled barriers ----------
// 128 WGs x 256 threads. role = bid>>6:
//  role 0 (A): h0[s] = gate([x[s] | h0[s-1]] @ [Wih0;Whh0] + b0)   K=1536
//  role 1 (B): h1[s] = gate([h0[s] | h1[s-1]] @ [Wih1;Whh1] + b1)  K=2048
// Each role: own 64-WG tree barrier per step. Cross-coupling:
//  B polls rootA >= (s+1)*8 before staging h0[s] (h0 ring depth 8),
//  A polls rootB for ring capacity only (rarely blocks).
__global__ void __launch_bounds__(256) gru_persist(char* __restrict__ ws, float* __restrict__ out)
{
  __shared__ __align__(16) char smem[139264];   // A-tile (<=128K) + 8K reduce

  const char* xbfb = ws + OFF_XBF;
  uint16_t* h0r = (uint16_t*)(ws + OFF_H0);
  uint16_t* h1r = (uint16_t*)(ws + OFF_H1);
  float*    h0f = (float*)(ws + OFF_H0F);
  float*    h1f = (float*)(ws + OFF_H1F);

  const int tid  = threadIdx.x;
  const int wave = tid >> 6;
  const int lane = tid & 63;
  const int bid  = blockIdx.x;
  const int role = bid >> 6;               // 0 = A (h0), 1 = B (h1)
  const int g    = bid & 63;

  // barrier lines
  uint32_t* grpCnt    = (uint32_t*)(ws + (size_t)role * 1024 + (size_t)(bid & 7) * 128);
  uint32_t* rootA     = (uint32_t*)(ws + 2048);
  uint32_t* rootB     = (uint32_t*)(ws + 2048 + 128);
  uint32_t* rootSelf  = role ? rootB : rootA;
  uint32_t* rootOther = role ? rootA : rootB;
  uint32_t* grpFlag   = (uint32_t*)(ws + 4096 + (size_t)role * 1024 + (size_t)(bid & 7) * 128);

  const int K2B   = role ? 4096 : 3072;    // bytes per A-tile row (K*2)
  const int nfrag = role ? 32 : 24;        // MFMAs per wave (K/16/4)
  const int kbase = wave * (role ? 512 : 384);
  float* red = (float*)(smem + (role ? 131072 : 98304));

  // ---- one-time: stage weight slice [32 gate cols][K] linearly, load breg ----
  {
    const char* wih = ws + (role ? OFF_WIH1 : OFF_WIH0);
    const char* whh = ws + (role ? OFF_WHH1 : OFF_WHH0);
    const int wihRow  = role ? 2048 : 1024;  // bytes per wih row
    const int nparts  = role ? 4 : 3;        // 1KB parts per col
    const int wsplit  = role ? 2 : 1;        // parts below this come from wih
    for (int rr = 0; rr < 8; ++rr) {
      int cc = wave * 8 + rr;
      int wr = (cc < 16) ? (16 * g + cc) : (1024 + 16 * g + (cc - 16));
      for (int p = 0; p < nparts; ++p) {
        const char* src = (p < wsplit)
            ? (wih + (size_t)wr * wihRow + (size_t)p * 1024 + lane * 16)
            : (whh + (size_t)wr * 2048 + (size_t)(p - wsplit) * 1024 + lane * 16);
        async16(src, smem + (size_t)cc * K2B + (size_t)p * 1024);
      }
    }
    asm volatile("s_waitcnt vmcnt(0)" ::: "memory");
    __syncthreads();
  }

  bf16x8 breg[32];
  {
    const int bcol  = lane & 31;
    const int khalf = (lane >> 5) * 8;
#pragma unroll
    for (int it = 0; it < 32; ++it) {
      if (it < nfrag) {
        int kk = kbase + it * 16 + khalf;
        breg[it] = __builtin_bit_cast(bf16x8,
                     *(const short8*)(smem + (size_t)bcol * K2B + (size_t)kk * 2));
      }
    }
  }
  __syncthreads();

  // per-lane output constants (C layout: col=lane&31, row=(r&3)+8*(r>>2)+4*(lane>>5))
  const int col  = lane & 31;
  const bool isU = (col < 16);
  const int gcol = isU ? (16 * g + col) : (1024 + 16 * g + (col - 16));
  const int rowb = (lane >> 5) * 4;
  const float bias_l = ((const float*)(ws + (role ? OFF_B1 : OFF_B0)))[gcol];
  const int hcol = 16 * g + (col & 15);

  // prologue: A issues x[0] prefetch into x-part of A-tile (weights already in regs)
  if (role == 0) {
    for (int rr = 0; rr < 8; ++rr) {
      int r = wave * 8 + rr;
      int lsw = (lane * 16) ^ ((r & 15) << 4);
      async16(xbfb + ((size_t)0 * 32 + r) * 1024 + lsw, smem + (size_t)r * 3072);
    }
  } else {
    // B waits for A to complete step 0 before staging h0[0]
    __syncthreads();
    if (tid == 0) {
      while (__hip_atomic_load(rootA, __ATOMIC_RELAXED, __HIP_MEMORY_SCOPE_AGENT) < 8u)
        __builtin_amdgcn_s_sleep(1);
      __builtin_amdgcn_fence(__ATOMIC_ACQUIRE, "agent");
    }
    __syncthreads();
  }

  for (int s = 0; s < 512; ++s) {
    // ---- wave0: exact fp32 h_prev prefetch (own-state ring, slot (s+1)&1) ----
    float hprev[16];
    if (wave == 0) {
      const float* hp = (role ? h1f : h0f) + (size_t)((s + 1) & 1) * 32768 + hcol;
#pragma unroll
      for (int r = 0; r < 16; ++r) {
        int b = (r & 3) + 8 * (r >> 2) + rowb;
        hprev[r] = hp[(size_t)b * 1024];
      }
    }

    // ---- stage A-tile (h parts; x part prefetched last step for role A) ----
    if (role == 0) {
      const char* h0base = ws + OFF_H0 + (size_t)((s + 7) & 7) * 65536;
      for (int rr = 0; rr < 8; ++rr) {
        int r = wave * 8 + rr;
        int lsw = (lane * 16) ^ ((r & 15) << 4);
        async16(h0base + (size_t)r * 2048 + lsw,        smem + (size_t)r * 3072 + 1024);
        async16(h0base + (size_t)r * 2048 + 1024 + lsw, smem + (size_t)r * 3072 + 2048);
      }
    } else {
      const char* h0base = ws + OFF_H0 + (size_t)(s & 7) * 65536;
      const char* h1base = ws + OFF_H1 + (size_t)((s + 1) & 1) * 65536;
      for (int rr = 0; rr < 8; ++rr) {
        int r = wave * 8 + rr;
        int lsw = (lane * 16) ^ ((r & 15) << 4);
        async16(h0base + (size_t)r * 2048 + lsw,        smem + (size_t)r * 4096);
        async16(h0base + (size_t)r * 2048 + 1024 + lsw, smem + (size_t)r * 4096 + 1024);
        async16(h1base + (size_t)r * 2048 + lsw,        smem + (size_t)r * 4096 + 2048);
        async16(h1base + (size_t)r * 2048 + 1024 + lsw, smem + (size_t)r * 4096 + 3072);
      }
    }
    asm volatile("s_waitcnt vmcnt(0)" ::: "memory");
    __syncthreads();

    // ---- MFMA: each wave does its K/4 slice, two interleaved acc chains ----
    f32x16 acc0, acc1;
#pragma unroll
    for (int r = 0; r < 16; ++r) { acc0[r] = 0.0f; acc1[r] = 0.0f; }
    {
      const int arow = lane & 31;
      const int sw   = (arow & 15) << 4;
      const int ka   = (kbase + (lane >> 5) * 8) * 2;
#pragma unroll
      for (int it = 0; it < 32; ++it) {
        if (it < nfrag) {
          int addr = (arow * K2B + ka + it * 32) ^ sw;
          bf16x8 a = __builtin_bit_cast(bf16x8, *(const short8*)(smem + addr));
          if (it & 1)
            acc1 = __builtin_amdgcn_mfma_f32_32x32x16_bf16(a, breg[it], acc1, 0, 0, 0);
          else
            acc0 = __builtin_amdgcn_mfma_f32_32x32x16_bf16(a, breg[it], acc0, 0, 0, 0);
        }
      }
    }
    f32x16 accT;
#pragma unroll
    for (int r = 0; r < 16; ++r) accT[r] = acc0[r] + acc1[r];

    __syncthreads();                        // all A-tile reads complete
    // waves 2,3 publish partials; role A also issues x[s+1] prefetch (x-part free now)
    if (wave >= 2) {
#pragma unroll
      for (int r = 0; r < 16; ++r) red[(wave - 2) * 1024 + r * 64 + lane] = accT[r];
    }
    if (role == 0) {
      int tn = (s + 1) & 511;
      for (int rr = 0; rr < 8; ++rr) {
        int r = wave * 8 + rr;
        int lsw = (lane * 16) ^ ((r & 15) << 4);
        async16(xbfb + ((size_t)tn * 32 + r) * 1024 + lsw, smem + (size_t)r * 3072);
      }
    }
    __syncthreads();
    if (wave < 2) {
#pragma unroll
      for (int r = 0; r < 16; ++r) accT[r] += red[wave * 1024 + r * 64 + lane];
    }
    __syncthreads();
    if (wave == 1) {
#pragma unroll
      for (int r = 0; r < 16; ++r) red[r * 64 + lane] = accT[r];
    }
    __syncthreads();
    if (wave == 0) {
#pragma unroll
      for (int r = 0; r < 16; ++r) accT[r] += red[r * 64 + lane];

      // gates -> activation -> h update
      uint16_t* hb;
      float*    hf;
      if (role == 0) {
        hb = h0r + (size_t)(s & 7) * 32768 + hcol;
        hf = h0f + (size_t)(s & 1) * 32768 + hcol;
      } else {
        hb = h1r + (size_t)(s & 1) * 32768 + hcol;
        hf = h1f + (size_t)(s & 1) * 32768 + hcol;
      }
#pragma unroll
      for (int r = 0; r < 16; ++r) {
        float c = accT[r] + bias_l;
        float v = isU ? (1.0f / (1.0f + __expf(-c))) : fmaxf(c, 0.0f);
        float p = __shfl_xor(v, 16);        // pair U-lane with its O-lane
        if (isU) {
          int b = (r & 3) + 8 * (r >> 2) + rowb;
          float hn = v * hprev[r] + (1.0f - v) * p;
          hb[(size_t)b * 1024] = f2bf(hn);
          hf[(size_t)b * 1024] = hn;
          if (role == 1)
            out[(size_t)b * (TT * HH) + (size_t)s * HH + hcol] = hn;
        }
      }
    }

    // ---- per-role 64-WG barrier (8 groups x 8) + cross-role coupling ----
    __syncthreads();
    if (tid == 0) {
      __builtin_amdgcn_fence(__ATOMIC_RELEASE, "agent");
      uint32_t old = __hip_atomic_fetch_add(grpCnt, 1u, __ATOMIC_RELAXED,
                                            __HIP_MEMORY_SCOPE_AGENT);
      if (old == (uint32_t)s * 8u + 7u) {
        __hip_atomic_fetch_add(rootSelf, 1u, __ATOMIC_RELAXED,
                               __HIP_MEMORY_SCOPE_AGENT);
        while (__hip_atomic_load(rootSelf, __ATOMIC_RELAXED,
                                 __HIP_MEMORY_SCOPE_AGENT) < (uint32_t)(s + 1) * 8u)
          __builtin_amdgcn_s_sleep(1);
        __hip_atomic_store(grpFlag, (uint32_t)(s + 1), __ATOMIC_RELAXED,
                           __HIP_MEMORY_SCOPE_AGENT);
      } else {
        while (__hip_atomic_load(grpFlag, __ATOMIC_RELAXED,
                                 __HIP_MEMORY_SCOPE_AGENT) < (uint32_t)(s + 1))
          __builtin_amdgcn_s_sleep(1);
      }
      if (role == 0) {
        // capacity: step s+1 writes h0[s+1], overwriting h0[s-6]; need B done with it
        if (s >= 7 && s < 511) {
          while (__hip_atomic_load(rootOther, __ATOMIC_RELAXED,
                                   __HIP_MEMORY_SCOPE_AGENT) < (uint32_t)(s - 6) * 8u)
            __builtin_amdgcn_s_sleep(1);
        }
      } else {
        // progress: step s+1 stages h0[s+1]; need A done with step s+1
        if (s < 511) {
          while (__hip_atomic_load(rootOther, __ATOMIC_RELAXED,
                                   __HIP_MEMORY_SCOPE_AGENT) < (uint32_t)(s + 2) * 8u)
            __builtin_amdgcn_s_sleep(1);
        }
      }
      __builtin_amdgcn_fence(__ATOMIC_ACQUIRE, "agent");
    }
    __syncthreads();
  }
}

extern "C" void kernel_launch(void* const* d_in, const int* in_sizes, int n_in,
                              void* d_out, int out_size, void* d_ws, size_t ws_size,
                              hipStream_t stream) {
  const float* x    = (const float*)d_in[0];
  const float* hx   = (const float*)d_in[1];
  const float* wih0 = (const float*)d_in[2];
  const float* whh0 = (const float*)d_in[3];
  const float* bih0 = (const float*)d_in[4];
  const float* bhh0 = (const float*)d_in[5];
  const float* wih1 = (const float*)d_in[6];
  const float* whh1 = (const float*)d_in[7];
  const float* bih1 = (const float*)d_in[8];
  const float* bhh1 = (const float*)d_in[9];
  char* ws   = (char*)d_ws;
  float* out = (float*)d_out;

  hipLaunchKernelGGL(prep_kernel, dim3(2048), dim3(256), 0, stream,
                     x, hx, wih0, whh0, bih0, bhh0, wih1, whh1, bih1, bhh1, ws);

  // 128 WGs, 136KB LDS each -> 1 WG/CU, trivially co-resident on 256 CUs.
  hipLaunchKernelGGL(gru_persist, dim3(128), dim3(256), 0, stream, ws, out);
}